// Round 6
// baseline (11405.381 us; speedup 1.0000x reference)
//
#include <hip/hip_runtime.h>

// LSTM: B=64, S=512, I=H=O=1024.  bf16 MFMA, fp32 accum.
// Persistent kernel, 64 blocks x 512 thr (8 waves), one block per CU.
// Waves 0-3 ("h-waves"): rows 16w..16w+15, FULL K=1024 of h @ W_h -> each lane
//   holds all 4 gate pre-activations for its (row,col): register-local epilogue,
//   c-state in registers, no reduction LDS.
// Waves 4-7 ("x-waves"): compute x_{t+1} @ W_i one step AHEAD (no h dep),
//   deposit into double-buffered LDS xpart buffer.
// W_h panel (64 cols x 1024 K bf16 = 128KB) staged once in LDS, XOR-swizzled.
// h exchanged via device-coherent (sc0 sc1) loads/stores; fence-free relaxed
// monotonic grid counter (4 adds/block/step, target 256*t).

typedef __bf16 bfv8 __attribute__((ext_vector_type(8)));
typedef float f32x4 __attribute__((ext_vector_type(4)));

__device__ __forceinline__ unsigned short f2bf(float x) {
    union { float f; unsigned int u; } v; v.f = x;
    unsigned int r = (v.u + 0x7FFFu + ((v.u >> 16) & 1u)) >> 16;
    return (unsigned short)r;
}

struct SrcPtrs { const float* p[9]; };

// Issue 8 coherent 16B loads (NO wait inside) at byte offsets O0..O7 from P.
#define ISSUE8(A, P, O0, O1, O2, O3, O4, O5, O6, O7)                         \
    asm volatile(                                                            \
        "global_load_dwordx4 %0, %8, off offset:" O0 " sc0 sc1\n\t"          \
        "global_load_dwordx4 %1, %8, off offset:" O1 " sc0 sc1\n\t"          \
        "global_load_dwordx4 %2, %8, off offset:" O2 " sc0 sc1\n\t"          \
        "global_load_dwordx4 %3, %8, off offset:" O3 " sc0 sc1\n\t"          \
        "global_load_dwordx4 %4, %8, off offset:" O4 " sc0 sc1\n\t"          \
        "global_load_dwordx4 %5, %8, off offset:" O5 " sc0 sc1\n\t"          \
        "global_load_dwordx4 %6, %8, off offset:" O6 " sc0 sc1\n\t"          \
        "global_load_dwordx4 %7, %8, off offset:" O7 " sc0 sc1"              \
        : "=&v"(A[0]), "=&v"(A[1]), "=&v"(A[2]), "=&v"(A[3]),                \
          "=&v"(A[4]), "=&v"(A[5]), "=&v"(A[6]), "=&v"(A[7])                 \
        : "v"(P)                                                             \
        : "memory")

// Wait until only N loads outstanding; ties the 8 regs so consumers can't hoist.
#define WAIT8(N, A)                                                          \
    do {                                                                     \
        asm volatile("s_waitcnt vmcnt(" N ")"                                \
                     : "+v"(A[0]), "+v"(A[1]), "+v"(A[2]), "+v"(A[3]),       \
                       "+v"(A[4]), "+v"(A[5]), "+v"(A[6]), "+v"(A[7])        \
                     :: "memory");                                           \
        __builtin_amdgcn_sched_barrier(0);                                   \
    } while (0)

// 8 k-steps of MFMA: A[j] vs swizzled LDS W_h fragments.
#define CONSUME8(A, IT0)                                                     \
    _Pragma("unroll")                                                        \
    for (int j = 0; j < 8; ++j) {                                            \
        _Pragma("unroll")                                                    \
        for (int n = 0; n < 4; ++n) {                                        \
            const int off = ((n * 16 + lr) << 11) +                          \
                            (((((IT0) + j) << 6) | (kq << 4)) ^ sxo);        \
            acc[n] = __builtin_amdgcn_mfma_f32_16x16x32_bf16(                \
                A[j], *(const bfv8*)(Lwh + off), acc[n], 0, 0, 0);           \
        }                                                                    \
    }

// ---------------------------------------------------------------------------
__global__ __launch_bounds__(256) void pack_weights(SrcPtrs sp,
                                                    unsigned short* __restrict__ Whp,
                                                    unsigned short* __restrict__ Wip,
                                                    unsigned short* __restrict__ Wy) {
    __shared__ float tile[64][65];
    const int z = blockIdx.z;
    const float* __restrict__ src = sp.p[z];
    const int n0 = blockIdx.x * 64, k0 = blockIdx.y * 64;
    const int tc = threadIdx.x & 63, tq = threadIdx.x >> 6;

    #pragma unroll
    for (int r = 0; r < 16; ++r) {
        const int kk = tq * 16 + r;
        tile[kk][tc] = src[(size_t)(k0 + kk) * 1024 + n0 + tc];
    }
    __syncthreads();
    #pragma unroll
    for (int r = 0; r < 16; ++r) {
        const int nl = tq * 16 + r;
        const int n = n0 + nl;
        const int k = k0 + tc;
        const unsigned short v = f2bf(tile[tc][nl]);
        if (z < 4) {
            Whp[(size_t)(((n >> 4) << 6) + (z << 4) + (n & 15)) * 1024 + k] = v;
        } else if (z < 8) {
            Wip[(size_t)(((n >> 4) << 6) + ((z - 4) << 4) + (n & 15)) * 1024 + k] = v;
        } else {
            Wy[(size_t)n * 1024 + k] = v;
        }
    }
}

// ---------------------------------------------------------------------------
__global__ __launch_bounds__(256) void convert_x(const float* __restrict__ x,
                                                 unsigned short* __restrict__ xT) {
    const size_t gid = (size_t)blockIdx.x * 256 + threadIdx.x;
    const int i0 = (int)(gid & 255) * 4;
    const size_t row = gid >> 8;            // dst row = t*64 + b
    const int t = (int)(row >> 6), b = (int)(row & 63);
    const float4 v = *reinterpret_cast<const float4*>(x + (((size_t)b * 512 + t) << 10) + i0);
    ushort4 o;
    o.x = f2bf(v.x); o.y = f2bf(v.y); o.z = f2bf(v.z); o.w = f2bf(v.w);
    *reinterpret_cast<ushort4*>(xT + (row << 10) + i0) = o;
}

// ---------------------------------------------------------------------------
__global__ __launch_bounds__(512) void lstm_seq(const unsigned short* __restrict__ xT,
                                                const unsigned short* __restrict__ Whp,
                                                const unsigned short* __restrict__ Wip,
                                                unsigned short* __restrict__ h0,
                                                unsigned short* __restrict__ h1,
                                                int* __restrict__ bar) {
    __shared__ struct {
        __align__(16) unsigned char wh[131072];   // swizzled W_h panel
        float xb[2][64][64];                      // xpart double buffer
    } L;
    unsigned char* Lwh = L.wh;

    const int tid = threadIdx.x;
    const int w = tid >> 6;           // 0..7
    const int lane = tid & 63;
    const int lr = lane & 15;
    const int kq = lane >> 4;
    const int blk = blockIdx.x;
    const bool isX = (w >= 4);
    const int sxo = (lr & 7) << 4;    // LDS XOR swizzle term

    // ---- stage swizzled W_h panel into LDS (all 512 threads) ----
    #pragma unroll
    for (int s = 0; s < 16; ++s) {
        const int c = s * 512 + tid;          // 0..8191 16B-chunks
        const int col = c >> 7, kc = c & 127;
        const bfv8 v = *reinterpret_cast<const bfv8*>(
            Whp + ((size_t)blk << 16) + col * 1024 + kc * 8);
        *(bfv8*)(Lwh + col * 2048 + ((kc * 16) ^ ((col & 7) << 4))) = v;
    }
    __syncthreads();

    // ---- x-projection worker: xpart(tt) -> L.xb[tt&1] ----
    auto xwork = [&](int tt) {
        const unsigned short* __restrict__ Ax =
            xT + ((size_t)tt << 16) + (size_t)(((w - 4) << 4) + lr) * 1024 + kq * 8;
        const unsigned short* __restrict__ Bw =
            Wip + ((size_t)blk << 16) + (size_t)lr * 1024 + kq * 8;
        f32x4 xacc[4] = {};
        #pragma unroll 4
        for (int it = 0; it < 32; ++it) {
            const bfv8 a = *reinterpret_cast<const bfv8*>(Ax + it * 32);
            #pragma unroll
            for (int n = 0; n < 4; ++n)
                xacc[n] = __builtin_amdgcn_mfma_f32_16x16x32_bf16(
                    a, *reinterpret_cast<const bfv8*>(Bw + n * 16384 + it * 32), xacc[n], 0, 0, 0);
        }
        #pragma unroll
        for (int n = 0; n < 4; ++n)
            #pragma unroll
            for (int r = 0; r < 4; ++r) {
                const int row = ((w - 4) << 4) + kq * 4 + r;
                L.xb[tt & 1][row][(n * 16 + lr) ^ ((row & 4) << 2)] = xacc[n][r];
            }
    };

    // prologue: xpart(0)
    if (isX) xwork(0);
    __syncthreads();

    float cst[4] = {0.f, 0.f, 0.f, 0.f};
    const int hoff = ((w << 4) + lr) * 1024 + kq * 8;   // h-wave A base (ushorts)

    for (int t = 0; t < 512; ++t) {
        const unsigned short* __restrict__ hin  = (t & 1) ? h1 : h0;
        unsigned short* __restrict__       hout = (t & 1) ? h0 : h1;

        if (!isX) {
            // wait for all blocks' h_{t-1} stores
            if (t > 0) {
                const int target = t << 8;
                while (__hip_atomic_load(bar, __ATOMIC_RELAXED, __HIP_MEMORY_SCOPE_AGENT) < target) { }
            }
            // depth-2 pipelined coherent h loads: rows 16w..+15, K=1024
            const unsigned short* hp = hin + hoff;
            f32x4 acc[4] = {};
            bfv8 a0[8], a1[8];
            ISSUE8(a0, hp, "0", "64", "128", "192", "256", "320", "384", "448");
            ISSUE8(a1, hp, "512", "576", "640", "704", "768", "832", "896", "960");
            WAIT8("8", a0);
            CONSUME8(a0, 0);
            ISSUE8(a0, hp, "1024", "1088", "1152", "1216", "1280", "1344", "1408", "1472");
            WAIT8("8", a1);
            CONSUME8(a1, 8);
            ISSUE8(a1, hp, "1536", "1600", "1664", "1728", "1792", "1856", "1920", "1984");
            WAIT8("8", a0);
            CONSUME8(a0, 16);
            WAIT8("0", a1);
            CONSUME8(a1, 24);

            // add x-projection partial from LDS
            #pragma unroll
            for (int n = 0; n < 4; ++n)
                #pragma unroll
                for (int r = 0; r < 4; ++r) {
                    const int row = (w << 4) + kq * 4 + r;
                    acc[n][r] += L.xb[t & 1][row][(n * 16 + lr) ^ ((row & 4) << 2)];
                }

            // register-local gate epilogue; c in registers
            unsigned short hs[4];
            #pragma unroll
            for (int r = 0; r < 4; ++r) {
                const float pi = acc[0][r], pf = acc[1][r], po = acc[2][r], pg = acc[3][r];
                const float ig = 1.f / (1.f + __expf(-pi));
                const float fg = 1.f / (1.f + __expf(-pf));
                const float og = 1.f / (1.f + __expf(-po));
                const float gg = 1.f - 2.f / (__expf(2.f * pg) + 1.f);
                const float cn = fg * cst[r] + ig * gg;
                cst[r] = cn;
                hs[r] = f2bf(og * (1.f - 2.f / (__expf(2.f * cn) + 1.f)));
            }
            // coherent h stores (4 scalar shorts), then signal
            unsigned short* hq = hout + (size_t)(((w << 4) + kq * 4) * 1024) + (blk << 4) + lr;
            #pragma unroll
            for (int r = 0; r < 4; ++r)
                asm volatile("global_store_short %0, %1, off sc0 sc1"
                             :: "v"(hq + r * 1024), "v"((unsigned)hs[r]) : "memory");
            asm volatile("s_waitcnt vmcnt(0)" ::: "memory");
            if (lane == 0)
                __hip_atomic_fetch_add(bar, 1, __ATOMIC_RELAXED, __HIP_MEMORY_SCOPE_AGENT);
        } else {
            if (t + 1 < 512) xwork(t + 1);
        }
        __syncthreads();   // publish xb[(t+1)&1]; order xb[t&1] reuse
    }
}

// ---------------------------------------------------------------------------
__global__ __launch_bounds__(256) void final_gemm(const unsigned short* __restrict__ h_in,
                                                  const unsigned short* __restrict__ WyT,
                                                  float* __restrict__ out) {
    const int tid = threadIdx.x;
    const int w = tid >> 6;
    const int lane = tid & 63;
    const int lr = lane & 15;
    const int kq = lane >> 4;
    const int c0 = blockIdx.x * 16;
    const int k0 = w * 256;

    f32x4 acc[4] = {};
    #pragma unroll 2
    for (int it = 0; it < 8; ++it) {
        const int k = k0 + it * 32 + kq * 8;
        const bfv8 bfr = *reinterpret_cast<const bfv8*>(WyT + (size_t)(c0 + lr) * 1024 + k);
        #pragma unroll
        for (int m = 0; m < 4; ++m) {
            const bfv8 a = *reinterpret_cast<const bfv8*>(h_in + (size_t)(m * 16 + lr) * 1024 + k);
            acc[m] = __builtin_amdgcn_mfma_f32_16x16x32_bf16(a, bfr, acc[m], 0, 0, 0);
        }
    }
    __shared__ float red[4][64][17];
    #pragma unroll
    for (int m = 0; m < 4; ++m)
        #pragma unroll
        for (int r = 0; r < 4; ++r)
            red[w][m * 16 + kq * 4 + r][lr] = acc[m][r];
    __syncthreads();
    #pragma unroll
    for (int u = 0; u < 4; ++u) {
        const int item = u * 256 + tid;
        const int b = item >> 4;
        const int jr = item & 15;
        const float s = red[0][b][jr] + red[1][b][jr] + red[2][b][jr] + red[3][b][jr];
        out[b * 1024 + c0 + jr] = s;
    }
}

// ---------------------------------------------------------------------------
extern "C" void kernel_launch(void* const* d_in, const int* in_sizes, int n_in,
                              void* d_out, int out_size, void* d_ws, size_t ws_size,
                              hipStream_t stream) {
    const float* x = (const float*)d_in[0];
    SrcPtrs sp;
    sp.p[0] = (const float*)d_in[1]; // W_hi
    sp.p[1] = (const float*)d_in[3]; // W_hf
    sp.p[2] = (const float*)d_in[5]; // W_ho
    sp.p[3] = (const float*)d_in[7]; // W_hg
    sp.p[4] = (const float*)d_in[2]; // W_ii
    sp.p[5] = (const float*)d_in[4]; // W_if
    sp.p[6] = (const float*)d_in[6]; // W_io
    sp.p[7] = (const float*)d_in[8]; // W_ig
    sp.p[8] = (const float*)d_in[9]; // W_y

    char* ws = (char*)d_ws;
    unsigned short* Whp = (unsigned short*)(ws + 0);          //  8 MB
    unsigned short* Wip = (unsigned short*)(ws + 8388608);    //  8 MB
    unsigned short* Wy  = (unsigned short*)(ws + 16777216);   //  2 MB
    unsigned short* xT  = (unsigned short*)(ws + 18874368);   // 64 MB
    unsigned short* h0  = (unsigned short*)(ws + 86245376);   // 128 KB
    unsigned short* h1  = (unsigned short*)(ws + 86376448);   // 128 KB
    int*            bar = (int*)(ws + 86507520);              // 4 B

    pack_weights<<<dim3(16, 16, 9), 256, 0, stream>>>(sp, Whp, Wip, Wy);
    convert_x<<<32768, 256, 0, stream>>>(x, xT);
    hipMemsetAsync(h0, 0, 64 * 1024 * 2, stream);
    hipMemsetAsync(bar, 0, 4, stream);

    lstm_seq<<<64, 512, 0, stream>>>(xT, Whp, Wip, h0, h1, bar);

    final_gemm<<<64, 256, 0, stream>>>(h0, Wy, (float*)d_out);
}

// Round 7
// 5552.475 us; speedup vs baseline: 2.0541x; 2.0541x over previous
//
#include <hip/hip_runtime.h>

// LSTM: B=64, S=512, I=H=O=1024.  bf16 MFMA, fp32 accum.
// Persistent kernel, 128 blocks x 512 thr (8 waves), 1 block/CU.
// Block owns 8 hidden units -> 32 fused gate cols (c = g*8 + j&7).
// W_h and W_i panels (64 KB each) staged once in XOR-swizzled LDS.
// h-waves 0-3: rows 16w..16w+15, full K=1024, register gates via one
//   shfl_xor(8) pair-exchange; c-state in registers.
// x-waves 4-7: x_{t+1} @ W_i one step ahead -> padded LDS xb buffer.
// h exchange: sc0 sc1 loads/stores (LLC-coherent, write-through), fence-free
// relaxed monotonic counter, lane0-of-wave-only spin (4 pollers/block).

typedef __bf16 bfv8 __attribute__((ext_vector_type(8)));
typedef float f32x4 __attribute__((ext_vector_type(4)));

__device__ __forceinline__ unsigned short f2bf(float x) {
    union { float f; unsigned int u; } v; v.f = x;
    unsigned int r = (v.u + 0x7FFFu + ((v.u >> 16) & 1u)) >> 16;
    return (unsigned short)r;
}

struct SrcPtrs { const float* p[9]; };

// Issue 8 coherent 16B loads (no wait) at byte offsets O0..O7 from P.
#define ISSUE8(A, P, O0, O1, O2, O3, O4, O5, O6, O7)                         \
    asm volatile(                                                            \
        "global_load_dwordx4 %0, %8, off offset:" O0 " sc0 sc1\n\t"          \
        "global_load_dwordx4 %1, %8, off offset:" O1 " sc0 sc1\n\t"          \
        "global_load_dwordx4 %2, %8, off offset:" O2 " sc0 sc1\n\t"          \
        "global_load_dwordx4 %3, %8, off offset:" O3 " sc0 sc1\n\t"          \
        "global_load_dwordx4 %4, %8, off offset:" O4 " sc0 sc1\n\t"          \
        "global_load_dwordx4 %5, %8, off offset:" O5 " sc0 sc1\n\t"          \
        "global_load_dwordx4 %6, %8, off offset:" O6 " sc0 sc1\n\t"          \
        "global_load_dwordx4 %7, %8, off offset:" O7 " sc0 sc1"              \
        : "=&v"(A[0]), "=&v"(A[1]), "=&v"(A[2]), "=&v"(A[3]),                \
          "=&v"(A[4]), "=&v"(A[5]), "=&v"(A[6]), "=&v"(A[7])                 \
        : "v"(P)                                                             \
        : "memory")

#define WAIT8(N, A)                                                          \
    do {                                                                     \
        asm volatile("s_waitcnt vmcnt(" N ")"                                \
                     : "+v"(A[0]), "+v"(A[1]), "+v"(A[2]), "+v"(A[3]),       \
                       "+v"(A[4]), "+v"(A[5]), "+v"(A[6]), "+v"(A[7])        \
                     :: "memory");                                           \
        __builtin_amdgcn_sched_barrier(0);                                   \
    } while (0)

// 8 k-steps x 2 N-tiles of MFMA vs swizzled LDS W_h.
#define CONSUME8(A, IT0)                                                     \
    _Pragma("unroll")                                                        \
    for (int j = 0; j < 8; ++j) {                                            \
        _Pragma("unroll")                                                    \
        for (int n = 0; n < 2; ++n) {                                        \
            const int off = ((n * 16 + lr) << 11) +                          \
                            (((((IT0) + j) << 6) | (kq << 4)) ^ sxo);        \
            acc[n] = __builtin_amdgcn_mfma_f32_16x16x32_bf16(                \
                A[j], *(const bfv8*)(Lwh + off), acc[n], 0, 0, 0);           \
        }                                                                    \
    }

// ---------------------------------------------------------------------------
// Weight pack: fp32 [k][n] -> bf16 panels. Block b (0..127) owns hidden
// j = 8b..8b+7; panel col c = g*8 + (j&7); layout [b*32 + c][k].
// ---------------------------------------------------------------------------
__global__ __launch_bounds__(256) void pack_weights(SrcPtrs sp,
                                                    unsigned short* __restrict__ Whp,
                                                    unsigned short* __restrict__ Wip,
                                                    unsigned short* __restrict__ Wy) {
    __shared__ float tile[64][65];
    const int z = blockIdx.z;
    const float* __restrict__ src = sp.p[z];
    const int n0 = blockIdx.x * 64, k0 = blockIdx.y * 64;
    const int tc = threadIdx.x & 63, tq = threadIdx.x >> 6;

    #pragma unroll
    for (int r = 0; r < 16; ++r) {
        const int kk = tq * 16 + r;
        tile[kk][tc] = src[(size_t)(k0 + kk) * 1024 + n0 + tc];
    }
    __syncthreads();
    #pragma unroll
    for (int r = 0; r < 16; ++r) {
        const int nl = tq * 16 + r;
        const int n = n0 + nl;
        const int k = k0 + tc;
        const unsigned short v = f2bf(tile[tc][nl]);
        if (z < 4) {
            Whp[(size_t)(((n >> 3) << 5) | (z << 3) | (n & 7)) * 1024 + k] = v;
        } else if (z < 8) {
            Wip[(size_t)(((n >> 3) << 5) | ((z - 4) << 3) | (n & 7)) * 1024 + k] = v;
        } else {
            Wy[(size_t)n * 1024 + k] = v;
        }
    }
}

// ---------------------------------------------------------------------------
__global__ __launch_bounds__(256) void convert_x(const float* __restrict__ x,
                                                 unsigned short* __restrict__ xT) {
    const size_t gid = (size_t)blockIdx.x * 256 + threadIdx.x;
    const int i0 = (int)(gid & 255) * 4;
    const size_t row = gid >> 8;            // dst row = t*64 + b
    const int t = (int)(row >> 6), b = (int)(row & 63);
    const float4 v = *reinterpret_cast<const float4*>(x + (((size_t)b * 512 + t) << 10) + i0);
    ushort4 o;
    o.x = f2bf(v.x); o.y = f2bf(v.y); o.z = f2bf(v.z); o.w = f2bf(v.w);
    *reinterpret_cast<ushort4*>(xT + (row << 10) + i0) = o;
}

// ---------------------------------------------------------------------------
__global__ __launch_bounds__(512) void lstm_seq(const unsigned short* __restrict__ xT,
                                                const unsigned short* __restrict__ Whp,
                                                const unsigned short* __restrict__ Wip,
                                                unsigned short* __restrict__ h0,
                                                unsigned short* __restrict__ h1,
                                                int* __restrict__ bar) {
    __shared__ struct {
        __align__(16) unsigned char wh[65536];   // swizzled W_h panel (32 cols x 1024)
        __align__(16) unsigned char wi[65536];   // swizzled W_i panel
        float xb[2][64][33];                     // xpart double buffer (padded)
    } L;
    unsigned char* Lwh = L.wh;

    const int tid = threadIdx.x;
    const int w = tid >> 6;           // 0..7
    const int lane = tid & 63;
    const int lr = lane & 15;
    const int kq = lane >> 4;
    const int blk = blockIdx.x;       // 0..127
    const int mw = w & 3;             // row group (batch rows 16*mw..+15)
    const bool isX = (w >= 4);
    const int sxo = (lr & 7) << 4;    // LDS XOR swizzle term

    // ---- stage both weight panels into swizzled LDS ----
    #pragma unroll
    for (int s = 0; s < 8; ++s) {
        const int c = s * 512 + tid;          // 0..4095 16B-chunks
        const int col = c >> 7, kc = c & 127;
        const int dst = col * 2048 + ((kc * 16) ^ ((col & 7) << 4));
        *(bfv8*)(L.wh + dst) = *(const bfv8*)(Whp + ((size_t)blk << 15) + col * 1024 + kc * 8);
        *(bfv8*)(L.wi + dst) = *(const bfv8*)(Wip + ((size_t)blk << 15) + col * 1024 + kc * 8);
    }
    __syncthreads();

    // ---- x-projection worker: xpart(tt) -> L.xb[tt&1] ----
    auto xwork = [&](int tt) {
        const unsigned short* __restrict__ Ax =
            xT + ((size_t)tt << 16) + (size_t)((mw << 4) + lr) * 1024 + kq * 8;
        f32x4 xacc[2] = {};
        #pragma unroll 16
        for (int it = 0; it < 32; ++it) {
            const bfv8 a = *reinterpret_cast<const bfv8*>(Ax + it * 32);
            #pragma unroll
            for (int n = 0; n < 2; ++n) {
                const int off = ((n * 16 + lr) << 11) + (((it << 6) | (kq << 4)) ^ sxo);
                xacc[n] = __builtin_amdgcn_mfma_f32_16x16x32_bf16(
                    a, *(const bfv8*)(L.wi + off), xacc[n], 0, 0, 0);
            }
        }
        #pragma unroll
        for (int n = 0; n < 2; ++n)
            #pragma unroll
            for (int r = 0; r < 4; ++r)
                L.xb[tt & 1][(mw << 4) + kq * 4 + r][n * 16 + lr] = xacc[n][r];
    };

    if (isX) xwork(0);
    __syncthreads();

    float cst[4] = {0.f, 0.f, 0.f, 0.f};
    const int hoff = ((mw << 4) + lr) * 1024 + kq * 8;

    for (int t = 0; t < 512; ++t) {
        const unsigned short* __restrict__ hin  = (t & 1) ? h1 : h0;
        unsigned short* __restrict__       hout = (t & 1) ? h0 : h1;

        if (!isX) {
            // wait for all blocks' step-(t-1) h stores: lane0-only poll
            if (t > 0 && lane == 0) {
                const int target = t << 9;    // 512 * t
                while (__hip_atomic_load(bar, __ATOMIC_RELAXED, __HIP_MEMORY_SCOPE_AGENT) < target)
                    __builtin_amdgcn_s_sleep(1);
            }
            asm volatile("" ::: "memory");

            // depth-2 pipelined coherent h loads: rows 16mw..+15, K=1024
            const unsigned short* hp = hin + hoff;
            f32x4 acc[2] = {};
            bfv8 a0[8], a1[8];
            ISSUE8(a0, hp, "0", "64", "128", "192", "256", "320", "384", "448");
            ISSUE8(a1, hp, "512", "576", "640", "704", "768", "832", "896", "960");
            WAIT8("8", a0);
            CONSUME8(a0, 0);
            ISSUE8(a0, hp, "1024", "1088", "1152", "1216", "1280", "1344", "1408", "1472");
            WAIT8("8", a1);
            CONSUME8(a1, 8);
            ISSUE8(a1, hp, "1536", "1600", "1664", "1728", "1792", "1856", "1920", "1984");
            WAIT8("8", a0);
            CONSUME8(a0, 16);
            WAIT8("0", a1);
            CONSUME8(a1, 24);

            // add x-projection partial
            #pragma unroll
            for (int n = 0; n < 2; ++n)
                #pragma unroll
                for (int r = 0; r < 4; ++r)
                    acc[n][r] += L.xb[t & 1][(mw << 4) + kq * 4 + r][n * 16 + lr];

            // gate pair-exchange + register-local epilogue.
            // lane lr<8: holds (i, o); partner lr^8 holds (f, g) for same j.
            const bool low = (lr & 8) == 0;
            unsigned short hsv[4];
            #pragma unroll
            for (int r = 0; r < 4; ++r) {
                const float s0 = acc[0][r], s1 = acc[1][r];
                const float x0 = __shfl_xor(s0, 8);
                const float x1 = __shfl_xor(s1, 8);
                const float pi = low ? s0 : x0;
                const float pf = low ? x0 : s0;
                const float po = low ? s1 : x1;
                const float pg = low ? x1 : s1;
                const float ig = 1.f / (1.f + __expf(-pi));
                const float fg = 1.f / (1.f + __expf(-pf));
                const float og = 1.f / (1.f + __expf(-po));
                const float gg = 1.f - 2.f / (__expf(2.f * pg) + 1.f);
                const float cn = fg * cst[r] + ig * gg;
                cst[r] = cn;
                hsv[r] = f2bf(og * (1.f - 2.f / (__expf(2.f * cn) + 1.f)));
            }
            if (low) {
                unsigned short* hq = hout + (size_t)((((mw << 4) + kq * 4)) * 1024) + (blk << 3) + lr;
                #pragma unroll
                for (int r = 0; r < 4; ++r)
                    asm volatile("global_store_short %0, %1, off sc0 sc1"
                                 :: "v"(hq + r * 1024), "v"((unsigned)hsv[r]) : "memory");
            }
            asm volatile("s_waitcnt vmcnt(0)" ::: "memory");
            if (lane == 0)
                __hip_atomic_fetch_add(bar, 1, __ATOMIC_RELAXED, __HIP_MEMORY_SCOPE_AGENT);
        } else {
            if (t + 1 < 512) xwork(t + 1);
        }
        __syncthreads();   // publish xb[(t+1)&1]; order xb reuse
    }
}

// ---------------------------------------------------------------------------
__global__ __launch_bounds__(256) void final_gemm(const unsigned short* __restrict__ h_in,
                                                  const unsigned short* __restrict__ WyT,
                                                  float* __restrict__ out) {
    const int tid = threadIdx.x;
    const int w = tid >> 6;
    const int lane = tid & 63;
    const int lr = lane & 15;
    const int kq = lane >> 4;
    const int c0 = blockIdx.x * 16;
    const int k0 = w * 256;

    f32x4 acc[4] = {};
    #pragma unroll 2
    for (int it = 0; it < 8; ++it) {
        const int k = k0 + it * 32 + kq * 8;
        const bfv8 bfr = *reinterpret_cast<const bfv8*>(WyT + (size_t)(c0 + lr) * 1024 + k);
        #pragma unroll
        for (int m = 0; m < 4; ++m) {
            const bfv8 a = *reinterpret_cast<const bfv8*>(h_in + (size_t)(m * 16 + lr) * 1024 + k);
            acc[m] = __builtin_amdgcn_mfma_f32_16x16x32_bf16(a, bfr, acc[m], 0, 0, 0);
        }
    }
    __shared__ float red[4][64][17];
    #pragma unroll
    for (int m = 0; m < 4; ++m)
        #pragma unroll
        for (int r = 0; r < 4; ++r)
            red[w][m * 16 + kq * 4 + r][lr] = acc[m][r];
    __syncthreads();
    #pragma unroll
    for (int u = 0; u < 4; ++u) {
        const int item = u * 256 + tid;
        const int b = item >> 4;
        const int jr = item & 15;
        const float s = red[0][b][jr] + red[1][b][jr] + red[2][b][jr] + red[3][b][jr];
        out[b * 1024 + c0 + jr] = s;
    }
}

// ---------------------------------------------------------------------------
extern "C" void kernel_launch(void* const* d_in, const int* in_sizes, int n_in,
                              void* d_out, int out_size, void* d_ws, size_t ws_size,
                              hipStream_t stream) {
    const float* x = (const float*)d_in[0];
    SrcPtrs sp;
    sp.p[0] = (const float*)d_in[1]; // W_hi
    sp.p[1] = (const float*)d_in[3]; // W_hf
    sp.p[2] = (const float*)d_in[5]; // W_ho
    sp.p[3] = (const float*)d_in[7]; // W_hg
    sp.p[4] = (const float*)d_in[2]; // W_ii
    sp.p[5] = (const float*)d_in[4]; // W_if
    sp.p[6] = (const float*)d_in[6]; // W_io
    sp.p[7] = (const float*)d_in[8]; // W_ig
    sp.p[8] = (const float*)d_in[9]; // W_y

    char* ws = (char*)d_ws;
    unsigned short* Whp = (unsigned short*)(ws + 0);          //  8 MB
    unsigned short* Wip = (unsigned short*)(ws + 8388608);    //  8 MB
    unsigned short* Wy  = (unsigned short*)(ws + 16777216);   //  2 MB
    unsigned short* xT  = (unsigned short*)(ws + 18874368);   // 64 MB
    unsigned short* h0  = (unsigned short*)(ws + 86245376);   // 128 KB
    unsigned short* h1  = (unsigned short*)(ws + 86376448);   // 128 KB
    int*            bar = (int*)(ws + 86507520);              // 4 B

    pack_weights<<<dim3(16, 16, 9), 256, 0, stream>>>(sp, Whp, Wip, Wy);
    convert_x<<<32768, 256, 0, stream>>>(x, xT);
    hipMemsetAsync(h0, 0, 64 * 1024 * 2, stream);
    hipMemsetAsync(bar, 0, 4, stream);

    lstm_seq<<<128, 512, 0, stream>>>(xT, Whp, Wip, h0, h1, bar);

    final_gemm<<<64, 256, 0, stream>>>(h0, Wy, (float*)d_out);
}

// Round 8
// 5073.869 us; speedup vs baseline: 2.2479x; 1.0943x over previous
//
#include <hip/hip_runtime.h>

// LSTM: B=64, S=512, I=H=O=1024.  bf16 MFMA, fp32 accum.
// Persistent kernel, 128 blocks x 512 thr (8 waves), 1 block/CU.
// Block owns 8 hidden units -> 32 fused gate cols (c = g*8 + j&7).
// W_h / W_i stored in GLOBAL already in MFMA-fragment-linear order, staged to
// LDS as a linear memcpy -> every ds_read_b128 is lane-stride-1 (0 conflicts).
// h-waves 0-3: rows 16w..16w+15, full K=1024; register gates via shfl_xor(8);
// c-state in registers. x-waves 4-7: x_{t+1} @ W_i one step ahead -> LDS xb
// in C-fragment lane order (producer lane == consumer lane).
// Barrier: per-block flag array (128 lines, plain sc0sc1 stores, parallel
// all-lane poll) -- no same-line atomic serialization.

typedef __bf16 bfv8 __attribute__((ext_vector_type(8)));
typedef float f32x4 __attribute__((ext_vector_type(4)));

__device__ __forceinline__ unsigned short f2bf(float x) {
    union { float f; unsigned int u; } v; v.f = x;
    unsigned int r = (v.u + 0x7FFFu + ((v.u >> 16) & 1u)) >> 16;
    return (unsigned short)r;
}

struct SrcPtrs { const float* p[9]; };

// Issue 8 coherent 16B loads (no wait) at byte offsets O0..O7 from P.
#define ISSUE8(A, P, O0, O1, O2, O3, O4, O5, O6, O7)                         \
    asm volatile(                                                            \
        "global_load_dwordx4 %0, %8, off offset:" O0 " sc0 sc1\n\t"          \
        "global_load_dwordx4 %1, %8, off offset:" O1 " sc0 sc1\n\t"          \
        "global_load_dwordx4 %2, %8, off offset:" O2 " sc0 sc1\n\t"          \
        "global_load_dwordx4 %3, %8, off offset:" O3 " sc0 sc1\n\t"          \
        "global_load_dwordx4 %4, %8, off offset:" O4 " sc0 sc1\n\t"          \
        "global_load_dwordx4 %5, %8, off offset:" O5 " sc0 sc1\n\t"          \
        "global_load_dwordx4 %6, %8, off offset:" O6 " sc0 sc1\n\t"          \
        "global_load_dwordx4 %7, %8, off offset:" O7 " sc0 sc1"              \
        : "=&v"(A[0]), "=&v"(A[1]), "=&v"(A[2]), "=&v"(A[3]),                \
          "=&v"(A[4]), "=&v"(A[5]), "=&v"(A[6]), "=&v"(A[7])                 \
        : "v"(P)                                                             \
        : "memory")

#define WAIT8(N, A)                                                          \
    do {                                                                     \
        asm volatile("s_waitcnt vmcnt(" N ")"                                \
                     : "+v"(A[0]), "+v"(A[1]), "+v"(A[2]), "+v"(A[3]),       \
                       "+v"(A[4]), "+v"(A[5]), "+v"(A[6]), "+v"(A[7])        \
                     :: "memory");                                           \
        __builtin_amdgcn_sched_barrier(0);                                   \
    } while (0)

// 8 k-steps x 2 N-tiles vs fragment-linear LDS W_h: lane-stride-1, 0 conflicts.
#define CONSUME8(A, IT0)                                                     \
    _Pragma("unroll")                                                        \
    for (int j = 0; j < 8; ++j) {                                            \
        _Pragma("unroll")                                                    \
        for (int n = 0; n < 2; ++n) {                                        \
            const int off = (((((IT0) + j) << 1) | n) << 10) + (lane << 4);  \
            acc[n] = __builtin_amdgcn_mfma_f32_16x16x32_bf16(                \
                A[j], *(const bfv8*)(Lwh + off), acc[n], 0, 0, 0);           \
        }                                                                    \
    }

// ---------------------------------------------------------------------------
// Weight pack: fp32 [k][n] -> bf16 fragment-linear panels.
// Block b (0..127) owns hidden j = 8b..8b+7; panel col c = g*8 + (j&7).
// ushort offset = (((b*32 + it)*2 + nn)*64 + lanef)*8 + kk,
//   it=k>>5, nn=c>>4, lanef=(c&15)|(((k>>3)&3)<<4), kk=k&7.
// ---------------------------------------------------------------------------
__global__ __launch_bounds__(256) void pack_weights(SrcPtrs sp,
                                                    unsigned short* __restrict__ Whp,
                                                    unsigned short* __restrict__ Wip,
                                                    unsigned short* __restrict__ Wy) {
    __shared__ float tile[64][65];
    const int z = blockIdx.z;
    const float* __restrict__ src = sp.p[z];
    const int n0 = blockIdx.x * 64, k0 = blockIdx.y * 64;
    const int tc = threadIdx.x & 63, tq = threadIdx.x >> 6;

    #pragma unroll
    for (int r = 0; r < 16; ++r) {
        const int kk = tq * 16 + r;
        tile[kk][tc] = src[(size_t)(k0 + kk) * 1024 + n0 + tc];
    }
    __syncthreads();
    #pragma unroll
    for (int r = 0; r < 16; ++r) {
        const int nl = tq * 16 + r;
        const int n = n0 + nl;
        const int k = k0 + tc;
        const unsigned short v = f2bf(tile[tc][nl]);
        if (z < 8) {
            const int g = z & 3;
            const int blk = n >> 3;
            const int c = (g << 3) | (n & 7);
            const int lanef = (c & 15) | (((k >> 3) & 3) << 4);
            const size_t off = ((size_t)((((blk << 5) | (k >> 5)) << 1) | (c >> 4)) << 9)
                             + (lanef << 3) + (k & 7);
            (z < 4 ? Whp : Wip)[off] = v;
        } else {
            Wy[(size_t)n * 1024 + k] = v;
        }
    }
}

// ---------------------------------------------------------------------------
__global__ __launch_bounds__(256) void convert_x(const float* __restrict__ x,
                                                 unsigned short* __restrict__ xT) {
    const size_t gid = (size_t)blockIdx.x * 256 + threadIdx.x;
    const int i0 = (int)(gid & 255) * 4;
    const size_t row = gid >> 8;            // dst row = t*64 + b
    const int t = (int)(row >> 6), b = (int)(row & 63);
    const float4 v = *reinterpret_cast<const float4*>(x + (((size_t)b * 512 + t) << 10) + i0);
    ushort4 o;
    o.x = f2bf(v.x); o.y = f2bf(v.y); o.z = f2bf(v.z); o.w = f2bf(v.w);
    *reinterpret_cast<ushort4*>(xT + (row << 10) + i0) = o;
}

// ---------------------------------------------------------------------------
__global__ __launch_bounds__(512) void lstm_seq(const unsigned short* __restrict__ xT,
                                                const unsigned short* __restrict__ Whp,
                                                const unsigned short* __restrict__ Wip,
                                                unsigned short* __restrict__ h0,
                                                unsigned short* __restrict__ h1,
                                                int* __restrict__ flg) {
    __shared__ struct {
        __align__(16) unsigned char wh[65536];   // fragment-linear W_h panel
        __align__(16) unsigned char wi[65536];   // fragment-linear W_i panel
        float xb[2][2][4][256];                  // xpart, C-fragment lane order
    } L;
    unsigned char* Lwh = L.wh;

    const int tid = threadIdx.x;
    const int w = tid >> 6;           // 0..7
    const int lane = tid & 63;
    const int lr = lane & 15;
    const int kq = lane >> 4;
    const int blk = blockIdx.x;       // 0..127
    const int mw = w & 3;             // batch-row group (rows 16*mw..+15)
    const bool isX = (w >= 4);

    // ---- stage both panels into LDS: pure linear memcpy ----
    #pragma unroll
    for (int s = 0; s < 8; ++s) {
        const int c = s * 512 + tid;          // 16B chunk 0..4095
        *(bfv8*)(L.wh + c * 16) = *(const bfv8*)(Whp + ((size_t)blk << 15) + c * 8);
        *(bfv8*)(L.wi + c * 16) = *(const bfv8*)(Wip + ((size_t)blk << 15) + c * 8);
    }
    __syncthreads();

    // ---- x-projection worker: xpart(tt) -> L.xb[tt&1] ----
    auto xwork = [&](int tt) {
        const unsigned short* __restrict__ Ax =
            xT + ((size_t)tt << 16) + (size_t)((mw << 4) + lr) * 1024 + kq * 8;
        f32x4 xacc[2] = {};
        #pragma unroll 8
        for (int it = 0; it < 32; ++it) {
            const bfv8 a = *reinterpret_cast<const bfv8*>(Ax + it * 32);
            #pragma unroll
            for (int n = 0; n < 2; ++n) {
                const int off = ((((it << 1) | n) << 10)) + (lane << 4);
                xacc[n] = __builtin_amdgcn_mfma_f32_16x16x32_bf16(
                    a, *(const bfv8*)(L.wi + off), xacc[n], 0, 0, 0);
            }
        }
        #pragma unroll
        for (int n = 0; n < 2; ++n)
            #pragma unroll
            for (int r = 0; r < 4; ++r)
                L.xb[tt & 1][n][r][(mw << 6) + lane] = xacc[n][r];
    };

    if (isX) xwork(0);
    __syncthreads();

    float cst[4] = {0.f, 0.f, 0.f, 0.f};
    const int hoff = ((mw << 4) + lr) * 1024 + kq * 8;

    for (int t = 0; t < 512; ++t) {
        const unsigned short* __restrict__ hin  = (t & 1) ? h1 : h0;
        unsigned short* __restrict__       hout = (t & 1) ? h0 : h1;

        if (!isX) {
            // parallel flag poll: all 128 producer flags >= t (2 per lane)
            if (t > 0) {
                const int* f0p = flg + (lane << 5);
                const int* f1p = flg + ((lane + 64) << 5);
                int f0, f1;
                do {
                    f0 = __hip_atomic_load(f0p, __ATOMIC_RELAXED, __HIP_MEMORY_SCOPE_AGENT);
                    f1 = __hip_atomic_load(f1p, __ATOMIC_RELAXED, __HIP_MEMORY_SCOPE_AGENT);
                } while (!__all(f0 >= t && f1 >= t));
            }

            // depth-2 pipelined coherent h loads: rows 16mw..+15, K=1024
            const unsigned short* hp = hin + hoff;
            f32x4 acc[2] = {};
            bfv8 a0[8], a1[8];
            ISSUE8(a0, hp, "0", "64", "128", "192", "256", "320", "384", "448");
            ISSUE8(a1, hp, "512", "576", "640", "704", "768", "832", "896", "960");
            WAIT8("8", a0);
            CONSUME8(a0, 0);
            ISSUE8(a0, hp, "1024", "1088", "1152", "1216", "1280", "1344", "1408", "1472");
            WAIT8("8", a1);
            CONSUME8(a1, 8);
            ISSUE8(a1, hp, "1536", "1600", "1664", "1728", "1792", "1856", "1920", "1984");
            WAIT8("8", a0);
            CONSUME8(a0, 16);
            WAIT8("0", a1);
            CONSUME8(a1, 24);

            // add x-projection partial (C-fragment lane order, conflict-free)
            #pragma unroll
            for (int n = 0; n < 2; ++n)
                #pragma unroll
                for (int r = 0; r < 4; ++r)
                    acc[n][r] += L.xb[t & 1][n][r][(mw << 6) + lane];

            // gate pair-exchange + register-local epilogue
            const bool low = (lr & 8) == 0;
            unsigned short hsv[4];
            #pragma unroll
            for (int r = 0; r < 4; ++r) {
                const float s0 = acc[0][r], s1 = acc[1][r];
                const float x0 = __shfl_xor(s0, 8);
                const float x1 = __shfl_xor(s1, 8);
                const float pi = low ? s0 : x0;
                const float pf = low ? x0 : s0;
                const float po = low ? s1 : x1;
                const float pg = low ? x1 : s1;
                const float ig = 1.f / (1.f + __expf(-pi));
                const float fg = 1.f / (1.f + __expf(-pf));
                const float og = 1.f / (1.f + __expf(-po));
                const float gg = 1.f - 2.f / (__expf(2.f * pg) + 1.f);
                const float cn = fg * cst[r] + ig * gg;
                cst[r] = cn;
                hsv[r] = f2bf(og * (1.f - 2.f / (__expf(2.f * cn) + 1.f)));
            }
            if (low) {
                unsigned short* hq = hout + (size_t)((((mw << 4) + kq * 4)) * 1024) + (blk << 3) + lr;
                #pragma unroll
                for (int r = 0; r < 4; ++r)
                    asm volatile("global_store_short %0, %1, off sc0 sc1"
                                 :: "v"(hq + r * 1024), "v"((unsigned)hsv[r]) : "memory");
            }
            asm volatile("s_waitcnt vmcnt(0)" ::: "memory");
        } else {
            if (t + 1 < 512) xwork(t + 1);
        }
        __syncthreads();   // all waves' h stores retired; xb[(t+1)&1] published

        // one plain coherent flag store per block per step (own 128B line)
        if (tid == 0)
            asm volatile("global_store_dword %0, %1, off sc0 sc1"
                         :: "v"(flg + (blk << 5)), "v"(t + 1) : "memory");
    }
}

// ---------------------------------------------------------------------------
__global__ __launch_bounds__(256) void final_gemm(const unsigned short* __restrict__ h_in,
                                                  const unsigned short* __restrict__ WyT,
                                                  float* __restrict__ out) {
    const int tid = threadIdx.x;
    const int w = tid >> 6;
    const int lane = tid & 63;
    const int lr = lane & 15;
    const int kq = lane >> 4;
    const int c0 = blockIdx.x * 16;
    const int k0 = w * 256;

    f32x4 acc[4] = {};
    #pragma unroll 2
    for (int it = 0; it < 8; ++it) {
        const int k = k0 + it * 32 + kq * 8;
        const bfv8 bfr = *reinterpret_cast<const bfv8*>(WyT + (size_t)(c0 + lr) * 1024 + k);
        #pragma unroll
        for (int m = 0; m < 4; ++m) {
            const bfv8 a = *reinterpret_cast<const bfv8*>(h_in + (size_t)(m * 16 + lr) * 1024 + k);
            acc[m] = __builtin_amdgcn_mfma_f32_16x16x32_bf16(a, bfr, acc[m], 0, 0, 0);
        }
    }
    __shared__ float red[4][64][17];
    #pragma unroll
    for (int m = 0; m < 4; ++m)
        #pragma unroll
        for (int r = 0; r < 4; ++r)
            red[w][m * 16 + kq * 4 + r][lr] = acc[m][r];
    __syncthreads();
    #pragma unroll
    for (int u = 0; u < 4; ++u) {
        const int item = u * 256 + tid;
        const int b = item >> 4;
        const int jr = item & 15;
        const float s = red[0][b][jr] + red[1][b][jr] + red[2][b][jr] + red[3][b][jr];
        out[b * 1024 + c0 + jr] = s;
    }
}

// ---------------------------------------------------------------------------
extern "C" void kernel_launch(void* const* d_in, const int* in_sizes, int n_in,
                              void* d_out, int out_size, void* d_ws, size_t ws_size,
                              hipStream_t stream) {
    const float* x = (const float*)d_in[0];
    SrcPtrs sp;
    sp.p[0] = (const float*)d_in[1]; // W_hi
    sp.p[1] = (const float*)d_in[3]; // W_hf
    sp.p[2] = (const float*)d_in[5]; // W_ho
    sp.p[3] = (const float*)d_in[7]; // W_hg
    sp.p[4] = (const float*)d_in[2]; // W_ii
    sp.p[5] = (const float*)d_in[4]; // W_if
    sp.p[6] = (const float*)d_in[6]; // W_io
    sp.p[7] = (const float*)d_in[8]; // W_ig
    sp.p[8] = (const float*)d_in[9]; // W_y

    char* ws = (char*)d_ws;
    unsigned short* Whp = (unsigned short*)(ws + 0);          //  8 MB
    unsigned short* Wip = (unsigned short*)(ws + 8388608);    //  8 MB
    unsigned short* Wy  = (unsigned short*)(ws + 16777216);   //  2 MB
    unsigned short* xT  = (unsigned short*)(ws + 18874368);   // 64 MB
    unsigned short* h0  = (unsigned short*)(ws + 86245376);   // 128 KB
    unsigned short* h1  = (unsigned short*)(ws + 86376448);   // 128 KB
    int*            flg = (int*)(ws + 86507520);              // 16 KB (128 x 128B)

    pack_weights<<<dim3(16, 16, 9), 256, 0, stream>>>(sp, Whp, Wip, Wy);
    convert_x<<<32768, 256, 0, stream>>>(x, xT);
    hipMemsetAsync(h0, 0, 64 * 1024 * 2, stream);
    hipMemsetAsync(flg, 0, 128 * 32 * 4, stream);

    lstm_seq<<<128, 512, 0, stream>>>(xT, Whp, Wip, h0, h1, flg);

    final_gemm<<<64, 256, 0, stream>>>(h0, Wy, (float*)d_out);
}

// Round 9
// 4687.490 us; speedup vs baseline: 2.4332x; 1.0824x over previous
//
#include <hip/hip_runtime.h>

// LSTM: B=64, S=512, I=H=O=1024.  bf16 MFMA, fp32 accum.
// Persistent kernel, 128 blocks x 512 thr (8 waves), 1 block/CU.
// Block owns 8 hidden units -> 32 fused gate cols (c = g*8 + j&7).
// W_h / W_i in MFMA-fragment-linear global order -> LDS linear memcpy ->
// all ds_read_b128 lane-stride-1 (0 bank conflicts, verified R8).
// h-waves 0-3: rows 16w..+15, full K=1024; gates via shfl_xor(8); c in regs.
// x-waves 4-7: x_{t+1} @ W_i one step ahead -> LDS xb (C-fragment lane order).
// h exchange: sc0 sc1 (LLC-coherent). R9: h stores coalesced to 16B dwordx4
// via LDS staging (was 512x 2B scattered -> WRITE_SIZE 2x amplification),
// and per-block flag posted EARLY (after h-store drain, before __syncthreads)
// via an LDS wave-completion counter.

typedef __bf16 bfv8 __attribute__((ext_vector_type(8)));
typedef float f32x4 __attribute__((ext_vector_type(4)));
typedef unsigned int u32v4 __attribute__((ext_vector_type(4)));

__device__ __forceinline__ unsigned short f2bf(float x) {
    union { float f; unsigned int u; } v; v.f = x;
    unsigned int r = (v.u + 0x7FFFu + ((v.u >> 16) & 1u)) >> 16;
    return (unsigned short)r;
}

struct SrcPtrs { const float* p[9]; };

// Issue 8 coherent 16B loads (no wait) at byte offsets O0..O7 from P.
#define ISSUE8(A, P, O0, O1, O2, O3, O4, O5, O6, O7)                         \
    asm volatile(                                                            \
        "global_load_dwordx4 %0, %8, off offset:" O0 " sc0 sc1\n\t"          \
        "global_load_dwordx4 %1, %8, off offset:" O1 " sc0 sc1\n\t"          \
        "global_load_dwordx4 %2, %8, off offset:" O2 " sc0 sc1\n\t"          \
        "global_load_dwordx4 %3, %8, off offset:" O3 " sc0 sc1\n\t"          \
        "global_load_dwordx4 %4, %8, off offset:" O4 " sc0 sc1\n\t"          \
        "global_load_dwordx4 %5, %8, off offset:" O5 " sc0 sc1\n\t"          \
        "global_load_dwordx4 %6, %8, off offset:" O6 " sc0 sc1\n\t"          \
        "global_load_dwordx4 %7, %8, off offset:" O7 " sc0 sc1"              \
        : "=&v"(A[0]), "=&v"(A[1]), "=&v"(A[2]), "=&v"(A[3]),                \
          "=&v"(A[4]), "=&v"(A[5]), "=&v"(A[6]), "=&v"(A[7])                 \
        : "v"(P)                                                             \
        : "memory")

#define WAIT8(N, A)                                                          \
    do {                                                                     \
        asm volatile("s_waitcnt vmcnt(" N ")"                                \
                     : "+v"(A[0]), "+v"(A[1]), "+v"(A[2]), "+v"(A[3]),       \
                       "+v"(A[4]), "+v"(A[5]), "+v"(A[6]), "+v"(A[7])        \
                     :: "memory");                                           \
        __builtin_amdgcn_sched_barrier(0);                                   \
    } while (0)

// 8 k-steps x 2 N-tiles vs fragment-linear LDS W_h: lane-stride-1, 0 conflicts.
#define CONSUME8(A, IT0)                                                     \
    _Pragma("unroll")                                                        \
    for (int j = 0; j < 8; ++j) {                                            \
        _Pragma("unroll")                                                    \
        for (int n = 0; n < 2; ++n) {                                        \
            const int off = (((((IT0) + j) << 1) | n) << 10) + (lane << 4);  \
            acc[n] = __builtin_amdgcn_mfma_f32_16x16x32_bf16(                \
                A[j], *(const bfv8*)(Lwh + off), acc[n], 0, 0, 0);           \
        }                                                                    \
    }

// ---------------------------------------------------------------------------
__global__ __launch_bounds__(256) void pack_weights(SrcPtrs sp,
                                                    unsigned short* __restrict__ Whp,
                                                    unsigned short* __restrict__ Wip,
                                                    unsigned short* __restrict__ Wy) {
    __shared__ float tile[64][65];
    const int z = blockIdx.z;
    const float* __restrict__ src = sp.p[z];
    const int n0 = blockIdx.x * 64, k0 = blockIdx.y * 64;
    const int tc = threadIdx.x & 63, tq = threadIdx.x >> 6;

    #pragma unroll
    for (int r = 0; r < 16; ++r) {
        const int kk = tq * 16 + r;
        tile[kk][tc] = src[(size_t)(k0 + kk) * 1024 + n0 + tc];
    }
    __syncthreads();
    #pragma unroll
    for (int r = 0; r < 16; ++r) {
        const int nl = tq * 16 + r;
        const int n = n0 + nl;
        const int k = k0 + tc;
        const unsigned short v = f2bf(tile[tc][nl]);
        if (z < 8) {
            const int g = z & 3;
            const int blk = n >> 3;
            const int c = (g << 3) | (n & 7);
            const int lanef = (c & 15) | (((k >> 3) & 3) << 4);
            const size_t off = ((size_t)((((blk << 5) | (k >> 5)) << 1) | (c >> 4)) << 9)
                             + (lanef << 3) + (k & 7);
            (z < 4 ? Whp : Wip)[off] = v;
        } else {
            Wy[(size_t)n * 1024 + k] = v;
        }
    }
}

// ---------------------------------------------------------------------------
__global__ __launch_bounds__(256) void convert_x(const float* __restrict__ x,
                                                 unsigned short* __restrict__ xT) {
    const size_t gid = (size_t)blockIdx.x * 256 + threadIdx.x;
    const int i0 = (int)(gid & 255) * 4;
    const size_t row = gid >> 8;            // dst row = t*64 + b
    const int t = (int)(row >> 6), b = (int)(row & 63);
    const float4 v = *reinterpret_cast<const float4*>(x + (((size_t)b * 512 + t) << 10) + i0);
    ushort4 o;
    o.x = f2bf(v.x); o.y = f2bf(v.y); o.z = f2bf(v.z); o.w = f2bf(v.w);
    *reinterpret_cast<ushort4*>(xT + (row << 10) + i0) = o;
}

// ---------------------------------------------------------------------------
__global__ __launch_bounds__(512) void lstm_seq(const unsigned short* __restrict__ xT,
                                                const unsigned short* __restrict__ Whp,
                                                const unsigned short* __restrict__ Wip,
                                                unsigned short* __restrict__ h0,
                                                unsigned short* __restrict__ h1,
                                                int* __restrict__ flg) {
    __shared__ struct {
        __align__(16) unsigned char wh[65536];   // fragment-linear W_h panel
        __align__(16) unsigned char wi[65536];   // fragment-linear W_i panel
        float xb[2][2][4][256];                  // xpart, C-fragment lane order
        __align__(16) unsigned short hs[64][8];  // h store-coalescing tile
        int sig;                                 // h-wave completion counter
    } L;
    unsigned char* Lwh = L.wh;

    const int tid = threadIdx.x;
    const int w = tid >> 6;           // 0..7
    const int lane = tid & 63;
    const int lr = lane & 15;
    const int kq = lane >> 4;
    const int blk = blockIdx.x;       // 0..127
    const int mw = w & 3;             // batch-row group (rows 16*mw..+15)
    const bool isX = (w >= 4);

    // ---- stage both panels into LDS: pure linear memcpy ----
    #pragma unroll
    for (int s = 0; s < 8; ++s) {
        const int c = s * 512 + tid;          // 16B chunk 0..4095
        *(bfv8*)(L.wh + c * 16) = *(const bfv8*)(Whp + ((size_t)blk << 15) + c * 8);
        *(bfv8*)(L.wi + c * 16) = *(const bfv8*)(Wip + ((size_t)blk << 15) + c * 8);
    }
    if (tid == 0) L.sig = 0;
    __syncthreads();

    // ---- x-projection worker: xpart(tt) -> L.xb[tt&1] ----
    auto xwork = [&](int tt) {
        const unsigned short* __restrict__ Ax =
            xT + ((size_t)tt << 16) + (size_t)((mw << 4) + lr) * 1024 + kq * 8;
        f32x4 xacc[2] = {};
        #pragma unroll 8
        for (int it = 0; it < 32; ++it) {
            const bfv8 a = *reinterpret_cast<const bfv8*>(Ax + it * 32);
            #pragma unroll
            for (int n = 0; n < 2; ++n) {
                const int off = ((((it << 1) | n) << 10)) + (lane << 4);
                xacc[n] = __builtin_amdgcn_mfma_f32_16x16x32_bf16(
                    a, *(const bfv8*)(L.wi + off), xacc[n], 0, 0, 0);
            }
        }
        #pragma unroll
        for (int n = 0; n < 2; ++n)
            #pragma unroll
            for (int r = 0; r < 4; ++r)
                L.xb[tt & 1][n][r][(mw << 6) + lane] = xacc[n][r];
    };

    if (isX) xwork(0);
    __syncthreads();

    float cst[4] = {0.f, 0.f, 0.f, 0.f};
    const int hoff = ((mw << 4) + lr) * 1024 + kq * 8;

    for (int t = 0; t < 512; ++t) {
        const unsigned short* __restrict__ hin  = (t & 1) ? h1 : h0;
        unsigned short* __restrict__       hout = (t & 1) ? h0 : h1;

        if (!isX) {
            // parallel flag poll: all 128 producer flags >= t (2 per lane)
            if (t > 0) {
                const int* f0p = flg + (lane << 5);
                const int* f1p = flg + ((lane + 64) << 5);
                int f0, f1;
                do {
                    f0 = __hip_atomic_load(f0p, __ATOMIC_RELAXED, __HIP_MEMORY_SCOPE_AGENT);
                    f1 = __hip_atomic_load(f1p, __ATOMIC_RELAXED, __HIP_MEMORY_SCOPE_AGENT);
                } while (!__all(f0 >= t && f1 >= t));
            }

            // depth-2 pipelined coherent h loads: rows 16mw..+15, K=1024
            const unsigned short* hp = hin + hoff;
            f32x4 acc[2] = {};
            bfv8 a0[8], a1[8];
            ISSUE8(a0, hp, "0", "64", "128", "192", "256", "320", "384", "448");
            ISSUE8(a1, hp, "512", "576", "640", "704", "768", "832", "896", "960");
            WAIT8("8", a0);
            CONSUME8(a0, 0);
            ISSUE8(a0, hp, "1024", "1088", "1152", "1216", "1280", "1344", "1408", "1472");
            WAIT8("8", a1);
            CONSUME8(a1, 8);
            ISSUE8(a1, hp, "1536", "1600", "1664", "1728", "1792", "1856", "1920", "1984");
            WAIT8("8", a0);
            CONSUME8(a0, 16);
            WAIT8("0", a1);
            CONSUME8(a1, 24);

            // add x-projection partial (C-fragment lane order, conflict-free)
            #pragma unroll
            for (int n = 0; n < 2; ++n)
                #pragma unroll
                for (int r = 0; r < 4; ++r)
                    acc[n][r] += L.xb[t & 1][n][r][(mw << 6) + lane];

            // gate pair-exchange + register-local epilogue
            const bool low = (lr & 8) == 0;
            unsigned short hsv[4];
            #pragma unroll
            for (int r = 0; r < 4; ++r) {
                const float s0 = acc[0][r], s1 = acc[1][r];
                const float x0 = __shfl_xor(s0, 8);
                const float x1 = __shfl_xor(s1, 8);
                const float pi = low ? s0 : x0;
                const float pf = low ? x0 : s0;
                const float po = low ? s1 : x1;
                const float pg = low ? x1 : s1;
                const float ig = 1.f / (1.f + __expf(-pi));
                const float fg = 1.f / (1.f + __expf(-pf));
                const float og = 1.f / (1.f + __expf(-po));
                const float gg = 1.f - 2.f / (__expf(2.f * pg) + 1.f);
                const float cn = fg * cst[r] + ig * gg;
                cst[r] = cn;
                hsv[r] = f2bf(og * (1.f - 2.f / (__expf(2.f * cn) + 1.f)));
            }

            // stage h in LDS (2B writes, own rows), then coalesced 16B stores
            if (low) {
                #pragma unroll
                for (int r = 0; r < 4; ++r)
                    L.hs[(mw << 4) + (kq << 2) + r][lr] = hsv[r];
            }
            asm volatile("s_waitcnt lgkmcnt(0)" ::: "memory");
            __builtin_amdgcn_sched_barrier(0);
            if (lane < 16) {
                const int row = (mw << 4) + lane;
                const u32v4 hv = *reinterpret_cast<const u32v4*>(&L.hs[row][0]);
                asm volatile("global_store_dwordx4 %0, %1, off sc0 sc1"
                             :: "v"(hout + (size_t)row * 1024 + (blk << 3)), "v"(hv)
                             : "memory");
            }
            asm volatile("s_waitcnt vmcnt(0)" ::: "memory");
            // early flag release: signal own wave done; wave 0 posts block flag
            if (lane == 0)
                atomicAdd(&L.sig, 1);
            if (w == 0 && lane == 0) {
                while (__hip_atomic_load(&L.sig, __ATOMIC_RELAXED,
                                         __HIP_MEMORY_SCOPE_WORKGROUP) < 4 * (t + 1)) { }
                asm volatile("global_store_dword %0, %1, off sc0 sc1"
                             :: "v"(flg + (blk << 5)), "v"(t + 1) : "memory");
            }
        } else {
            if (t + 1 < 512) xwork(t + 1);
        }
        __syncthreads();   // xb[(t+1)&1] published; order xb reuse
    }
}

// ---------------------------------------------------------------------------
__global__ __launch_bounds__(256) void final_gemm(const unsigned short* __restrict__ h_in,
                                                  const unsigned short* __restrict__ WyT,
                                                  float* __restrict__ out) {
    const int tid = threadIdx.x;
    const int w = tid >> 6;
    const int lane = tid & 63;
    const int lr = lane & 15;
    const int kq = lane >> 4;
    const int c0 = blockIdx.x * 16;
    const int k0 = w * 256;

    f32x4 acc[4] = {};
    #pragma unroll 2
    for (int it = 0; it < 8; ++it) {
        const int k = k0 + it * 32 + kq * 8;
        const bfv8 bfr = *reinterpret_cast<const bfv8*>(WyT + (size_t)(c0 + lr) * 1024 + k);
        #pragma unroll
        for (int m = 0; m < 4; ++m) {
            const bfv8 a = *reinterpret_cast<const bfv8*>(h_in + (size_t)(m * 16 + lr) * 1024 + k);
            acc[m] = __builtin_amdgcn_mfma_f32_16x16x32_bf16(a, bfr, acc[m], 0, 0, 0);
        }
    }
    __shared__ float red[4][64][17];
    #pragma unroll
    for (int m = 0; m < 4; ++m)
        #pragma unroll
        for (int r = 0; r < 4; ++r)
            red[w][m * 16 + kq * 4 + r][lr] = acc[m][r];
    __syncthreads();
    #pragma unroll
    for (int u = 0; u < 4; ++u) {
        const int item = u * 256 + tid;
        const int b = item >> 4;
        const int jr = item & 15;
        const float s = red[0][b][jr] + red[1][b][jr] + red[2][b][jr] + red[3][b][jr];
        out[b * 1024 + c0 + jr] = s;
    }
}

// ---------------------------------------------------------------------------
extern "C" void kernel_launch(void* const* d_in, const int* in_sizes, int n_in,
                              void* d_out, int out_size, void* d_ws, size_t ws_size,
                              hipStream_t stream) {
    const float* x = (const float*)d_in[0];
    SrcPtrs sp;
    sp.p[0] = (const float*)d_in[1]; // W_hi
    sp.p[1] = (const float*)d_in[3]; // W_hf
    sp.p[2] = (const float*)d_in[5]; // W_ho
    sp.p[3] = (const float*)d_in[7]; // W_hg
    sp.p[4] = (const float*)d_in[2]; // W_ii
    sp.p[5] = (const float*)d_in[4]; // W_if
    sp.p[6] = (const float*)d_in[6]; // W_io
    sp.p[7] = (const float*)d_in[8]; // W_ig
    sp.p[8] = (const float*)d_in[9]; // W_y

    char* ws = (char*)d_ws;
    unsigned short* Whp = (unsigned short*)(ws + 0);          //  8 MB
    unsigned short* Wip = (unsigned short*)(ws + 8388608);    //  8 MB
    unsigned short* Wy  = (unsigned short*)(ws + 16777216);   //  2 MB
    unsigned short* xT  = (unsigned short*)(ws + 18874368);   // 64 MB
    unsigned short* h0  = (unsigned short*)(ws + 86245376);   // 128 KB
    unsigned short* h1  = (unsigned short*)(ws + 86376448);   // 128 KB
    int*            flg = (int*)(ws + 86507520);              // 16 KB (128 x 128B)

    pack_weights<<<dim3(16, 16, 9), 256, 0, stream>>>(sp, Whp, Wip, Wy);
    convert_x<<<32768, 256, 0, stream>>>(x, xT);
    hipMemsetAsync(h0, 0, 64 * 1024 * 2, stream);
    hipMemsetAsync(flg, 0, 128 * 32 * 4, stream);

    lstm_seq<<<128, 512, 0, stream>>>(xT, Whp, Wip, h0, h1, flg);

    final_gemm<<<64, 256, 0, stream>>>(h0, Wy, (float*)d_out);
}

// Round 10
// 4452.274 us; speedup vs baseline: 2.5617x; 1.0528x over previous
//
#include <hip/hip_runtime.h>

// LSTM: B=64, S=512, I=H=O=1024.  bf16 MFMA, fp32 accum.
// Persistent kernel, 128 blocks x 512 thr (8 waves), 1 block/CU.
// Block owns 8 hidden units -> 32 fused gate cols (c = g*8 + j&7).
// W_h / W_i in MFMA-fragment-linear global order -> LDS linear memcpy ->
// all ds_read_b128 lane-stride-1 (0 bank conflicts, verified R8).
// h-waves 0-3: rows 16w..+15, full K=1024; gates via shfl_xor(8); c in regs.
// x-waves 4-7: x_{t+1} @ W_i one step ahead -> LDS xb (C-fragment lane order).
// R10: (a) flag polls split into 4 groups of 32, pipelined with h-load issue
// (K-chunk g is produced exactly by blocks 32g..32g+31); (b) s_sleep backoff
// in polls; (c) flag posted by the LAST h-wave to drain (atomicAdd==4t+3),
// removing the wave0 LDS spin from the critical chain.

typedef __bf16 bfv8 __attribute__((ext_vector_type(8)));
typedef float f32x4 __attribute__((ext_vector_type(4)));
typedef unsigned int u32v4 __attribute__((ext_vector_type(4)));

__device__ __forceinline__ unsigned short f2bf(float x) {
    union { float f; unsigned int u; } v; v.f = x;
    unsigned int r = (v.u + 0x7FFFu + ((v.u >> 16) & 1u)) >> 16;
    return (unsigned short)r;
}

struct SrcPtrs { const float* p[9]; };

// Issue 8 coherent 16B loads (no wait) at byte offsets O0..O7 from P.
#define ISSUE8(A, P, O0, O1, O2, O3, O4, O5, O6, O7)                         \
    asm volatile(                                                            \
        "global_load_dwordx4 %0, %8, off offset:" O0 " sc0 sc1\n\t"          \
        "global_load_dwordx4 %1, %8, off offset:" O1 " sc0 sc1\n\t"          \
        "global_load_dwordx4 %2, %8, off offset:" O2 " sc0 sc1\n\t"          \
        "global_load_dwordx4 %3, %8, off offset:" O3 " sc0 sc1\n\t"          \
        "global_load_dwordx4 %4, %8, off offset:" O4 " sc0 sc1\n\t"          \
        "global_load_dwordx4 %5, %8, off offset:" O5 " sc0 sc1\n\t"          \
        "global_load_dwordx4 %6, %8, off offset:" O6 " sc0 sc1\n\t"          \
        "global_load_dwordx4 %7, %8, off offset:" O7 " sc0 sc1"              \
        : "=&v"(A[0]), "=&v"(A[1]), "=&v"(A[2]), "=&v"(A[3]),                \
          "=&v"(A[4]), "=&v"(A[5]), "=&v"(A[6]), "=&v"(A[7])                 \
        : "v"(P)                                                             \
        : "memory")

#define WAIT8(N, A)                                                          \
    do {                                                                     \
        asm volatile("s_waitcnt vmcnt(" N ")"                                \
                     : "+v"(A[0]), "+v"(A[1]), "+v"(A[2]), "+v"(A[3]),       \
                       "+v"(A[4]), "+v"(A[5]), "+v"(A[6]), "+v"(A[7])        \
                     :: "memory");                                           \
        __builtin_amdgcn_sched_barrier(0);                                   \
    } while (0)

// 8 k-steps x 2 N-tiles vs fragment-linear LDS W_h: lane-stride-1, 0 conflicts.
#define CONSUME8(A, IT0)                                                     \
    _Pragma("unroll")                                                        \
    for (int j = 0; j < 8; ++j) {                                            \
        _Pragma("unroll")                                                    \
        for (int n = 0; n < 2; ++n) {                                        \
            const int off = (((((IT0) + j) << 1) | n) << 10) + (lane << 4);  \
            acc[n] = __builtin_amdgcn_mfma_f32_16x16x32_bf16(                \
                A[j], *(const bfv8*)(Lwh + off), acc[n], 0, 0, 0);           \
        }                                                                    \
    }

// ---------------------------------------------------------------------------
__global__ __launch_bounds__(256) void pack_weights(SrcPtrs sp,
                                                    unsigned short* __restrict__ Whp,
                                                    unsigned short* __restrict__ Wip,
                                                    unsigned short* __restrict__ Wy) {
    __shared__ float tile[64][65];
    const int z = blockIdx.z;
    const float* __restrict__ src = sp.p[z];
    const int n0 = blockIdx.x * 64, k0 = blockIdx.y * 64;
    const int tc = threadIdx.x & 63, tq = threadIdx.x >> 6;

    #pragma unroll
    for (int r = 0; r < 16; ++r) {
        const int kk = tq * 16 + r;
        tile[kk][tc] = src[(size_t)(k0 + kk) * 1024 + n0 + tc];
    }
    __syncthreads();
    #pragma unroll
    for (int r = 0; r < 16; ++r) {
        const int nl = tq * 16 + r;
        const int n = n0 + nl;
        const int k = k0 + tc;
        const unsigned short v = f2bf(tile[tc][nl]);
        if (z < 8) {
            const int g = z & 3;
            const int blk = n >> 3;
            const int c = (g << 3) | (n & 7);
            const int lanef = (c & 15) | (((k >> 3) & 3) << 4);
            const size_t off = ((size_t)((((blk << 5) | (k >> 5)) << 1) | (c >> 4)) << 9)
                             + (lanef << 3) + (k & 7);
            (z < 4 ? Whp : Wip)[off] = v;
        } else {
            Wy[(size_t)n * 1024 + k] = v;
        }
    }
}

// ---------------------------------------------------------------------------
__global__ __launch_bounds__(256) void convert_x(const float* __restrict__ x,
                                                 unsigned short* __restrict__ xT) {
    const size_t gid = (size_t)blockIdx.x * 256 + threadIdx.x;
    const int i0 = (int)(gid & 255) * 4;
    const size_t row = gid >> 8;            // dst row = t*64 + b
    const int t = (int)(row >> 6), b = (int)(row & 63);
    const float4 v = *reinterpret_cast<const float4*>(x + (((size_t)b * 512 + t) << 10) + i0);
    ushort4 o;
    o.x = f2bf(v.x); o.y = f2bf(v.y); o.z = f2bf(v.z); o.w = f2bf(v.w);
    *reinterpret_cast<ushort4*>(xT + (row << 10) + i0) = o;
}

// ---------------------------------------------------------------------------
__global__ __launch_bounds__(512) void lstm_seq(const unsigned short* __restrict__ xT,
                                                const unsigned short* __restrict__ Whp,
                                                const unsigned short* __restrict__ Wip,
                                                unsigned short* __restrict__ h0,
                                                unsigned short* __restrict__ h1,
                                                int* __restrict__ flg) {
    __shared__ struct {
        __align__(16) unsigned char wh[65536];   // fragment-linear W_h panel
        __align__(16) unsigned char wi[65536];   // fragment-linear W_i panel
        float xb[2][2][4][256];                  // xpart, C-fragment lane order
        __align__(16) unsigned short hs[64][8];  // h store-coalescing tile
        int sig;                                 // h-wave completion counter
    } L;
    unsigned char* Lwh = L.wh;

    const int tid = threadIdx.x;
    const int w = tid >> 6;           // 0..7
    const int lane = tid & 63;
    const int lr = lane & 15;
    const int kq = lane >> 4;
    const int blk = blockIdx.x;       // 0..127
    const int mw = w & 3;             // batch-row group (rows 16*mw..+15)
    const bool isX = (w >= 4);

    // ---- stage both panels into LDS: pure linear memcpy ----
    #pragma unroll
    for (int s = 0; s < 8; ++s) {
        const int c = s * 512 + tid;          // 16B chunk 0..4095
        *(bfv8*)(L.wh + c * 16) = *(const bfv8*)(Whp + ((size_t)blk << 15) + c * 8);
        *(bfv8*)(L.wi + c * 16) = *(const bfv8*)(Wip + ((size_t)blk << 15) + c * 8);
    }
    if (tid == 0) L.sig = 0;
    __syncthreads();

    // ---- x-projection worker: xpart(tt) -> L.xb[tt&1] ----
    auto xwork = [&](int tt) {
        const unsigned short* __restrict__ Ax =
            xT + ((size_t)tt << 16) + (size_t)((mw << 4) + lr) * 1024 + kq * 8;
        f32x4 xacc[2] = {};
        #pragma unroll 8
        for (int it = 0; it < 32; ++it) {
            const bfv8 a = *reinterpret_cast<const bfv8*>(Ax + it * 32);
            #pragma unroll
            for (int n = 0; n < 2; ++n) {
                const int off = ((((it << 1) | n) << 10)) + (lane << 4);
                xacc[n] = __builtin_amdgcn_mfma_f32_16x16x32_bf16(
                    a, *(const bfv8*)(L.wi + off), xacc[n], 0, 0, 0);
            }
        }
        #pragma unroll
        for (int n = 0; n < 2; ++n)
            #pragma unroll
            for (int r = 0; r < 4; ++r)
                L.xb[tt & 1][n][r][(mw << 6) + lane] = xacc[n][r];
    };

    if (isX) xwork(0);
    __syncthreads();

    float cst[4] = {0.f, 0.f, 0.f, 0.f};
    const int hoff = ((mw << 4) + lr) * 1024 + kq * 8;

    for (int t = 0; t < 512; ++t) {
        const unsigned short* __restrict__ hin  = (t & 1) ? h1 : h0;
        unsigned short* __restrict__       hout = (t & 1) ? h0 : h1;

        if (!isX) {
            // poll one 32-producer group (covers h cols 256g..256g+255)
            auto poll32 = [&](int g) {
                if (t == 0) return;
                const int* fp = flg + (((g << 5) + (lane & 31)) << 5);
                for (;;) {
                    const int f = __hip_atomic_load(fp, __ATOMIC_RELAXED,
                                                    __HIP_MEMORY_SCOPE_AGENT);
                    if (__all(f >= t)) break;
                    __builtin_amdgcn_s_sleep(1);
                }
            };

            // pipelined: poll group g, then issue the K-chunk it produced
            const unsigned short* hp = hin + hoff;
            f32x4 acc[2] = {};
            bfv8 a0[8], a1[8];
            poll32(0);
            ISSUE8(a0, hp, "0", "64", "128", "192", "256", "320", "384", "448");
            poll32(1);
            ISSUE8(a1, hp, "512", "576", "640", "704", "768", "832", "896", "960");
            WAIT8("8", a0);
            CONSUME8(a0, 0);
            poll32(2);
            ISSUE8(a0, hp, "1024", "1088", "1152", "1216", "1280", "1344", "1408", "1472");
            WAIT8("8", a1);
            CONSUME8(a1, 8);
            poll32(3);
            ISSUE8(a1, hp, "1536", "1600", "1664", "1728", "1792", "1856", "1920", "1984");
            WAIT8("8", a0);
            CONSUME8(a0, 16);
            WAIT8("0", a1);
            CONSUME8(a1, 24);

            // add x-projection partial (C-fragment lane order, conflict-free)
            #pragma unroll
            for (int n = 0; n < 2; ++n)
                #pragma unroll
                for (int r = 0; r < 4; ++r)
                    acc[n][r] += L.xb[t & 1][n][r][(mw << 6) + lane];

            // gate pair-exchange + register-local epilogue
            const bool low = (lr & 8) == 0;
            unsigned short hsv[4];
            #pragma unroll
            for (int r = 0; r < 4; ++r) {
                const float s0 = acc[0][r], s1 = acc[1][r];
                const float x0 = __shfl_xor(s0, 8);
                const float x1 = __shfl_xor(s1, 8);
                const float pi = low ? s0 : x0;
                const float pf = low ? x0 : s0;
                const float po = low ? s1 : x1;
                const float pg = low ? x1 : s1;
                const float ig = 1.f / (1.f + __expf(-pi));
                const float fg = 1.f / (1.f + __expf(-pf));
                const float og = 1.f / (1.f + __expf(-po));
                const float gg = 1.f - 2.f / (__expf(2.f * pg) + 1.f);
                const float cn = fg * cst[r] + ig * gg;
                cst[r] = cn;
                hsv[r] = f2bf(og * (1.f - 2.f / (__expf(2.f * cn) + 1.f)));
            }

            // stage h in LDS (2B writes, own rows), then coalesced 16B stores
            if (low) {
                #pragma unroll
                for (int r = 0; r < 4; ++r)
                    L.hs[(mw << 4) + (kq << 2) + r][lr] = hsv[r];
            }
            asm volatile("s_waitcnt lgkmcnt(0)" ::: "memory");
            __builtin_amdgcn_sched_barrier(0);
            if (lane < 16) {
                const int row = (mw << 4) + lane;
                const u32v4 hv = *reinterpret_cast<const u32v4*>(&L.hs[row][0]);
                asm volatile("global_store_dwordx4 %0, %1, off sc0 sc1"
                             :: "v"(hout + (size_t)row * 1024 + (blk << 3)), "v"(hv)
                             : "memory");
            }
            asm volatile("s_waitcnt vmcnt(0)" ::: "memory");
            // last h-wave to drain posts the block flag (no secondary spin)
            if (lane == 0) {
                const int old = atomicAdd(&L.sig, 1);
                if (old == 4 * t + 3)
                    asm volatile("global_store_dword %0, %1, off sc0 sc1"
                                 :: "v"(flg + (blk << 5)), "v"(t + 1) : "memory");
            }
        } else {
            if (t + 1 < 512) xwork(t + 1);
        }
        __syncthreads();   // xb[(t+1)&1] published; order xb reuse
    }
}

// ---------------------------------------------------------------------------
__global__ __launch_bounds__(256) void final_gemm(const unsigned short* __restrict__ h_in,
                                                  const unsigned short* __restrict__ WyT,
                                                  float* __restrict__ out) {
    const int tid = threadIdx.x;
    const int w = tid >> 6;
    const int lane = tid & 63;
    const int lr = lane & 15;
    const int kq = lane >> 4;
    const int c0 = blockIdx.x * 16;
    const int k0 = w * 256;

    f32x4 acc[4] = {};
    #pragma unroll 2
    for (int it = 0; it < 8; ++it) {
        const int k = k0 + it * 32 + kq * 8;
        const bfv8 bfr = *reinterpret_cast<const bfv8*>(WyT + (size_t)(c0 + lr) * 1024 + k);
        #pragma unroll
        for (int m = 0; m < 4; ++m) {
            const bfv8 a = *reinterpret_cast<const bfv8*>(h_in + (size_t)(m * 16 + lr) * 1024 + k);
            acc[m] = __builtin_amdgcn_mfma_f32_16x16x32_bf16(a, bfr, acc[m], 0, 0, 0);
        }
    }
    __shared__ float red[4][64][17];
    #pragma unroll
    for (int m = 0; m < 4; ++m)
        #pragma unroll
        for (int r = 0; r < 4; ++r)
            red[w][m * 16 + kq * 4 + r][lr] = acc[m][r];
    __syncthreads();
    #pragma unroll
    for (int u = 0; u < 4; ++u) {
        const int item = u * 256 + tid;
        const int b = item >> 4;
        const int jr = item & 15;
        const float s = red[0][b][jr] + red[1][b][jr] + red[2][b][jr] + red[3][b][jr];
        out[b * 1024 + c0 + jr] = s;
    }
}

// ---------------------------------------------------------------------------
extern "C" void kernel_launch(void* const* d_in, const int* in_sizes, int n_in,
                              void* d_out, int out_size, void* d_ws, size_t ws_size,
                              hipStream_t stream) {
    const float* x = (const float*)d_in[0];
    SrcPtrs sp;
    sp.p[0] = (const float*)d_in[1]; // W_hi
    sp.p[1] = (const float*)d_in[3]; // W_hf
    sp.p[2] = (const float*)d_in[5]; // W_ho
    sp.p[3] = (const float*)d_in[7]; // W_hg
    sp.p[4] = (const float*)d_in[2]; // W_ii
    sp.p[5] = (const float*)d_in[4]; // W_if
    sp.p[6] = (const float*)d_in[6]; // W_io
    sp.p[7] = (const float*)d_in[8]; // W_ig
    sp.p[8] = (const float*)d_in[9]; // W_y

    char* ws = (char*)d_ws;
    unsigned short* Whp = (unsigned short*)(ws + 0);          //  8 MB
    unsigned short* Wip = (unsigned short*)(ws + 8388608);    //  8 MB
    unsigned short* Wy  = (unsigned short*)(ws + 16777216);   //  2 MB
    unsigned short* xT  = (unsigned short*)(ws + 18874368);   // 64 MB
    unsigned short* h0  = (unsigned short*)(ws + 86245376);   // 128 KB
    unsigned short* h1  = (unsigned short*)(ws + 86376448);   // 128 KB
    int*            flg = (int*)(ws + 86507520);              // 16 KB (128 x 128B)

    pack_weights<<<dim3(16, 16, 9), 256, 0, stream>>>(sp, Whp, Wip, Wy);
    convert_x<<<32768, 256, 0, stream>>>(x, xT);
    hipMemsetAsync(h0, 0, 64 * 1024 * 2, stream);
    hipMemsetAsync(flg, 0, 128 * 32 * 4, stream);

    lstm_seq<<<128, 512, 0, stream>>>(xT, Whp, Wip, h0, h1, flg);

    final_gemm<<<64, 256, 0, stream>>>(h0, Wy, (float*)d_out);
}